// Round 12
// baseline (155.710 us; speedup 1.0000x reference)
//
#include <hip/hip_runtime.h>
#include <math.h>
#include <stdint.h>

// Chamfer distance, B=8, N=M=8192, D=3, fp32 -> MFMA reformulation.
// dist2 = |q|^2 + (|t|^2 - 2 q.t). One 16x16 tile = 2 chained
// mfma_f32_16x16x32_bf16 with 2-term bf16 splits (full 4-term product:
// ah*bh + ah*bl + al*bh + al*bl, residual ~2^-17) + |t|^2 split folded into
// 2 K-slots; |q|^2 added per query in the epilogue.
// LAYOUT-AMBIGUITY-PROOF: only K-slots {0..3} (lane-group g=0, elems 0-3) and
// {28..31} (g=3, elems 4-7) are used — the "consecutive-8" and "two stacked
// K=16 blocks" interpretations of the gfx950 A/B operand map AGREE on exactly
// these slots; all other lanes/elems are zero. C-layout: col=lane&15,
// row=(lane>>4)*4+reg (m89-verified).
// R1-R10 history: VALU formulation saturates at ~82us (58% of the 48us
// static floor = the chip's practical fp32-FMA efficiency); matrix pipe is
// the only remaining lever.

#define B_  8
#define N_  8192

typedef short  s16x8 __attribute__((ext_vector_type(8)));
typedef float  f32x4 __attribute__((ext_vector_type(4)));
typedef int    i32x4 __attribute__((ext_vector_type(4)));

__device__ __forceinline__ unsigned bf16rn(float f) {
    unsigned u = __float_as_uint(f);
    return (u + 0x7FFFu + ((u >> 16) & 1u)) >> 16;   // round-nearest-even
}
__device__ __forceinline__ float bf16tof(unsigned h) {
    return __uint_as_float(h << 16);
}
__device__ __forceinline__ int pk2(unsigned lo, unsigned hi) {
    return (int)(lo | (hi << 16));
}
union frag_u { i32x4 i; s16x8 h; };
__device__ __forceinline__ s16x8 mkfrag(int w0, int w1, int w2, int w3) {
    frag_u u; u.i = (i32x4){w0, w1, w2, w3}; return u.h;
}

// ---- prep: per point, write the 4 8B A-fragment half-rows to global ----
// A layout per target-tile (16 targets): [m(2)][half(2)][r(16)] x 8B = 512B.
//   m0 lo: [ath0,ath1,ath2,ath0]   m0 hi: [ath1,ath2,atl0,atl1]
//   m1 lo: [atl2,atl0,atl1,atl2]   m1 hi: [tnh, tnl, 0, 0]
// (at = -2t split hi/lo; tn = |t|^2 split hi/lo)
__global__ void prep_kernel(const float* __restrict__ x, const float* __restrict__ y,
                            char* __restrict__ AX, char* __restrict__ AY) {
    int i = blockIdx.x * blockDim.x + threadIdx.x;
    if (i >= 2 * B_ * N_) return;
    const float* src = (i < B_ * N_) ? x : y;
    char* A = (i < B_ * N_) ? AX : AY;
    int idx = i & (B_ * N_ - 1);
    const float* p = src + (long)idx * 3;
    float t0 = p[0], t1 = p[1], t2 = p[2];
    float a0 = -2.f * t0, a1 = -2.f * t1, a2 = -2.f * t2;
    unsigned h0 = bf16rn(a0), h1 = bf16rn(a1), h2 = bf16rn(a2);
    unsigned l0 = bf16rn(a0 - bf16tof(h0));
    unsigned l1 = bf16rn(a1 - bf16tof(h1));
    unsigned l2 = bf16rn(a2 - bf16tof(h2));
    float tn = fmaf(t0, t0, fmaf(t1, t1, t2 * t2));
    unsigned nh = bf16rn(tn);
    unsigned nl = bf16rn(tn - bf16tof(nh));
    int tile = idx >> 4, r = idx & 15;               // 8192/16=512 tiles/batch, contiguous
    char* base = A + ((long)tile << 9) + (r << 3);
    *(int2*)(base      ) = make_int2(pk2(h0, h1), pk2(h2, h0));
    *(int2*)(base + 128) = make_int2(pk2(h1, h2), pk2(l0, l1));
    *(int2*)(base + 256) = make_int2(pk2(l2, l0), pk2(l1, l2));
    *(int2*)(base + 384) = make_int2(pk2(nh, nl), 0);
}

// ---- minpass: grid (64 qb, 8 b, 4 = sblk*1 + dir*2), 256 thr = 4 waves ----
// All 4 waves share 128 queries (8 B-frags in VGPRs); wave wv scans the
// 1024-target chunk s = sblk*4+wv (64 tiles). Per tile: 2 masked 8B global
// loads (L2-resident A-rows) + 8x(2 chained MFMA + 2 min3).
__global__ __launch_bounds__(256)
void minpass_kernel(const float* __restrict__ x, const float* __restrict__ y,
                    const char* __restrict__ AX, const char* __restrict__ AY,
                    float* __restrict__ partX, float* __restrict__ partY) {
    __shared__ float minbuf[4][128];
    const int qb   = blockIdx.x;
    const int b    = blockIdx.y;
    const int sblk = blockIdx.z & 1;
    const int dir  = blockIdx.z >> 1;          // 0: q=x,t=y  1: q=y,t=x
    const float* qpts = dir ? y : x;
    const char*  Ab   = dir ? AX : AY;
    float*       part = dir ? partY : partX;

    const int tid = threadIdx.x;
    const int l   = tid & 63;
    const int wv  = tid >> 6;
    const int g   = l >> 4;
    const int c   = l & 15;
    const int s   = sblk * 4 + wv;

    // ---- B fragments: 8 frags x 16 queries, built once into VGPRs ----
    s16x8 b1[8], b2[8];
    const int ONE2 = pk2(0x3F80u, 0x3F80u);   // bf16 1.0 pair
    #pragma unroll
    for (int f = 0; f < 8; ++f) {
        const float* qp = qpts + (long)(b * N_ + qb * 128 + f * 16 + c) * 3;
        float q0 = qp[0], q1 = qp[1], q2 = qp[2];
        unsigned h0 = bf16rn(q0), h1 = bf16rn(q1), h2 = bf16rn(q2);
        unsigned u0 = bf16rn(q0 - bf16tof(h0));
        unsigned u1 = bf16rn(q1 - bf16tof(h1));
        unsigned u2 = bf16rn(q2 - bf16tof(h2));
        int w0 = pk2(h0, h1), w1 = pk2(h2, u0);      // B1 g0: [qh0 qh1 qh2 ql0]
        int w2 = pk2(u1, u2), w3 = pk2(h0, h1);      // B1 g3: [ql1 ql2 qh0 qh1]
        b1[f] = mkfrag(g == 0 ? w0 : 0, g == 0 ? w1 : 0,
                       g == 3 ? w2 : 0, g == 3 ? w3 : 0);
        int v0 = pk2(h2, u0), v1 = pk2(u1, u2);      // B2 g0: [qh2 ql0 ql1 ql2]
        b2[f] = mkfrag(g == 0 ? v0 : 0, g == 0 ? v1 : 0,
                       g == 3 ? ONE2 : 0, 0);        // B2 g3: [1 1 0 0]
    }

    float m[8];
    #pragma unroll
    for (int f = 0; f < 8; ++f) m[f] = __builtin_inff();

    const bool gsel = (g == 0) || (g == 3);
    const int  goff = (g == 3) ? 128 : 0;
    const char* pa = Ab + ((long)(b * 512 + s * 64) << 9) + goff + (c << 3);

    int2 c1 = make_int2(0, 0), c2 = make_int2(0, 0);
    if (gsel) { c1 = *(const int2*)(pa); c2 = *(const int2*)(pa + 256); }

    for (int t = 0; t < 64; ++t) {
        // prefetch next tile's A half-rows (last iter overshoots into slop)
        int2 n1 = make_int2(0, 0), n2 = make_int2(0, 0);
        const char* pn = pa + ((long)(t + 1) << 9);
        if (gsel) { n1 = *(const int2*)(pn); n2 = *(const int2*)(pn + 256); }

        s16x8 a1 = mkfrag(g == 0 ? c1.x : 0, g == 0 ? c1.y : 0,
                          g == 3 ? c1.x : 0, g == 3 ? c1.y : 0);
        s16x8 a2 = mkfrag(g == 0 ? c2.x : 0, g == 0 ? c2.y : 0,
                          g == 3 ? c2.x : 0, g == 3 ? c2.y : 0);
        #pragma unroll
        for (int f = 0; f < 8; ++f) {
            f32x4 acc = __builtin_amdgcn_mfma_f32_16x16x32_bf16(
                a1, b1[f], (f32x4){0.f, 0.f, 0.f, 0.f}, 0, 0, 0);
            acc = __builtin_amdgcn_mfma_f32_16x16x32_bf16(a2, b2[f], acc, 0, 0, 0);
            float u = fminf(fminf(acc.x, acc.y), acc.z);   // v_min3
            m[f] = fminf(fminf(u, acc.w), m[f]);           // v_min3
        }
        c1 = n1; c2 = n2;
    }

    // combine the 4 row-bands (lane groups) per query
    #pragma unroll
    for (int f = 0; f < 8; ++f) {
        m[f] = fminf(m[f], __shfl_xor(m[f], 16, 64));
        m[f] = fminf(m[f], __shfl_xor(m[f], 32, 64));
    }
    if (l < 16) {
        #pragma unroll
        for (int f = 0; f < 8; ++f) minbuf[wv][f * 16 + l] = m[f];
    }
    __syncthreads();
    if (tid < 128) {   // merge 4 waves' chunks, add |q|^2, clamp, store
        float v = fminf(fminf(minbuf[0][tid], minbuf[1][tid]),
                        fminf(minbuf[2][tid], minbuf[3][tid]));
        const float* qp = qpts + (long)(b * N_ + qb * 128 + tid) * 3;
        float xn = fmaf(qp[0], qp[0], fmaf(qp[1], qp[1], qp[2] * qp[2]));
        part[sblk * (B_ * N_) + b * N_ + qb * 128 + tid] = fmaxf(v + xn, 0.f);
    }
}

// min over the 2 sblk partials, deterministic block sum
__global__ __launch_bounds__(256)
void merge_kernel(const float* __restrict__ partX, const float* __restrict__ partY,
                  float* __restrict__ bsum, int BN) {
    const int gq = blockIdx.x * blockDim.x + threadIdx.x;
    const float* base = (gq < BN) ? (partX + gq) : (partY + (gq - BN));
    float mv = fminf(base[0], base[BN]);
    for (int off = 32; off > 0; off >>= 1)
        mv += __shfl_down(mv, off, 64);
    __shared__ float wsum[4];
    if ((threadIdx.x & 63) == 0) wsum[threadIdx.x >> 6] = mv;
    __syncthreads();
    if (threadIdx.x == 0)
        bsum[blockIdx.x] = (wsum[0] + wsum[1]) + (wsum[2] + wsum[3]);
}

__global__ __launch_bounds__(64)
void final_kernel(const float* __restrict__ bsum, float* __restrict__ out,
                  int nb, float scale) {
    float s = 0.0f;
    for (int k = threadIdx.x; k < nb; k += 64)
        s += bsum[k];
    for (int off = 32; off > 0; off >>= 1)
        s += __shfl_down(s, off, 64);
    if (threadIdx.x == 0) out[0] = s * scale;
}

extern "C" void kernel_launch(void* const* d_in, const int* in_sizes, int n_in,
                              void* d_out, int out_size, void* d_ws, size_t ws_size,
                              hipStream_t stream) {
    const float* x = (const float*)d_in[0];  // [8, 8192, 3]
    const float* y = (const float*)d_in[1];  // [8, 8192, 3]
    float* out = (float*)d_out;

    const size_t ASZ = (size_t)(B_ * N_ / 16) * 512 + 512;   // 2MB + slop
    char*  AX    = (char*)d_ws;
    char*  AY    = AX + ASZ;
    float* partX = (float*)(AY + ASZ);
    float* partY = partX + 2 * (B_ * N_);
    float* bsum  = partY + 2 * (B_ * N_);

    prep_kernel<<<(2 * B_ * N_ + 255) / 256, 256, 0, stream>>>(x, y, AX, AY);

    // grid: (qb=64, b=8, sblk+2*dir=4) = 2048 blocks
    minpass_kernel<<<dim3(64, B_, 4), 256, 0, stream>>>(x, y, AX, AY, partX, partY);

    const int BN = B_ * N_;               // 65536
    const int nb = 2 * BN / 256;          // 512
    merge_kernel<<<nb, 256, 0, stream>>>(partX, partY, bsum, BN);
    final_kernel<<<1, 64, 0, stream>>>(bsum, out, nb, 1.0f / 65536.0f);
}